// Round 14
// baseline (399.824 us; speedup 1.0000x reference)
//
#include <hip/hip_runtime.h>
#include <math.h>

// Problem constants
#define BQ 2
#define NQ 2048
#define CQ 768
#define HQ 12
#define DQ 64
#define MQ 64
#define LQ 32
#define C3 2304
#define BH 24
#define BN 4096

typedef short bf16x8 __attribute__((ext_vector_type(8)));
typedef float f32x4 __attribute__((ext_vector_type(4)));

__device__ inline void atomicMaxPosF(float* addr, float v) {
  atomicMax((int*)addr, __float_as_int(v));
}

// split f32 into bf16 hi + bf16 lo (truncation; combined rel err ~2^-17)
__device__ inline void f2pair(float f, ushort& hi, ushort& lo) {
  union { float f; unsigned u; } a; a.f = f;
  hi = (ushort)(a.u >> 16);
  union { unsigned u; float f; } h; h.u = ((unsigned)hi) << 16;
  union { float f; unsigned u; } b; b.f = f - h.f;
  lo = (ushort)(b.u >> 16);
}

// ===========================================================================
// 128x128 bf16x3 NT GEMM on pre-converted bf16 hi/lo planes.
// XCD-aware block swizzle (T1): each XCD gets a contiguous chunk of the grid
// so consecutive tiles' shared B-panels stay hot in that XCD's private L2.
// All gemm_bt3 grids are multiples of 8 (576 / 192 / 6144) -> bijective.
// ===========================================================================
__device__ inline void stage_plane(const ushort* __restrict__ g, int ld,
                                   ushort* l, int t) {
#pragma unroll
  for (int i = 0; i < 4; ++i) {
    int flat = t + i * 256;
    int row = flat >> 3;
    int ch = (flat & 7) ^ (row & 7);
    __builtin_amdgcn_global_load_lds(
        (const __attribute__((address_space(1))) void*)(g + (size_t)row * ld + ch * 8),
        (__attribute__((address_space(3))) void*)(l + flat * 8), 16, 0, 0);
  }
}

__device__ inline bf16x8 rdfrag(const ushort* p, int row, int kb) {
  return *(const bf16x8*)((const char*)p + row * 128 + (kb ^ ((row & 7) << 4)));
}

__global__ __launch_bounds__(256) void gemm_bt3(
    const ushort* __restrict__ Ah, const ushort* __restrict__ Al,
    const ushort* __restrict__ Bh, const ushort* __restrict__ Bl,
    const float* __restrict__ bias, float* __restrict__ C,
    int Kdim, int lda, int ldb, int ldc, int qscale, int zH,
    long long sAb, long long sAh, long long sBb, long long sBh,
    long long sCb, long long sCh)
{
  __shared__ __align__(16) ushort lds[32768];
  ushort* LAh = lds;
  ushort* LAl = lds + 8192;
  ushort* LBh = lds + 16384;
  ushort* LBl = lds + 24576;
  const int t = threadIdx.x;
  // XCD swizzle: linear id -> contiguous work chunk per XCD
  const int nwgx = gridDim.x, nwgy = gridDim.y;
  const int nwg = nwgx * nwgy * gridDim.z;
  const int lid = blockIdx.x + nwgx * (blockIdx.y + nwgy * blockIdx.z);
  const int cpx = nwg >> 3;
  const int swz = (lid & 7) * cpx + (lid >> 3);
  const int bx = swz % nwgx;
  const int tmp2 = swz / nwgx;
  const int by = tmp2 % nwgy;
  const int bz = tmp2 / nwgy;
  const int b = bz / zH, h = bz % zH;
  const size_t aoff = (size_t)b * sAb + (size_t)h * sAh + (size_t)bx * 128 * lda;
  const size_t boff = (size_t)b * sBb + (size_t)h * sBh + (size_t)by * 128 * ldb;
  const ushort* pAh = Ah + aoff;
  const ushort* pAl = Al + aoff;
  const ushort* pBh = Bh + boff;
  const ushort* pBl = Bl + boff;
  float* Cp = C + (size_t)b * sCb + (size_t)h * sCh;
  const int lane = t & 63, wv = t >> 6, wm = wv >> 1, wn = wv & 1;
  f32x4 zz = {0.f, 0.f, 0.f, 0.f};
  f32x4 acc[4][4] = {{zz, zz, zz, zz}, {zz, zz, zz, zz},
                     {zz, zz, zz, zz}, {zz, zz, zz, zz}};
  for (int k0 = 0; k0 < Kdim; k0 += 64) {
    stage_plane(pAh + k0, lda, LAh, t);
    stage_plane(pAl + k0, lda, LAl, t);
    stage_plane(pBh + k0, ldb, LBh, t);
    stage_plane(pBl + k0, ldb, LBl, t);
    __syncthreads();
#pragma unroll
    for (int kh = 0; kh < 2; ++kh) {
      const int kb = kh * 64 + ((lane >> 4) * 16);
      bf16x8 aH[4], aL[4], bHf[4], bLf[4];
#pragma unroll
      for (int i = 0; i < 4; ++i) {
        int ra = wm * 64 + i * 16 + (lane & 15);
        int rb = wn * 64 + i * 16 + (lane & 15);
        aH[i] = rdfrag(LAh, ra, kb);
        aL[i] = rdfrag(LAl, ra, kb);
        bHf[i] = rdfrag(LBh, rb, kb);
        bLf[i] = rdfrag(LBl, rb, kb);
      }
#pragma unroll
      for (int i = 0; i < 4; ++i)
#pragma unroll
        for (int j = 0; j < 4; ++j) {
          acc[i][j] = __builtin_amdgcn_mfma_f32_16x16x32_bf16(aH[i], bHf[j], acc[i][j], 0, 0, 0);
          acc[i][j] = __builtin_amdgcn_mfma_f32_16x16x32_bf16(aH[i], bLf[j], acc[i][j], 0, 0, 0);
          acc[i][j] = __builtin_amdgcn_mfma_f32_16x16x32_bf16(aL[i], bHf[j], acc[i][j], 0, 0, 0);
        }
    }
    __syncthreads();
  }
#pragma unroll
  for (int i = 0; i < 4; ++i)
#pragma unroll
    for (int j = 0; j < 4; ++j) {
      int row = bx * 128 + wm * 64 + i * 16 + (lane >> 4) * 4;
      int col = by * 128 + wn * 64 + j * 16 + (lane & 15);
      float badd = bias ? bias[col] : 0.0f;
      float sc = (qscale && col < CQ) ? 0.125f : 1.0f;
#pragma unroll
      for (int r = 0; r < 4; ++r)
        Cp[(size_t)(row + r) * ldc + col] = acc[i][j][r] * sc + badd;
    }
}

// ===========================================================================
// f32 -> bf16 hi/lo planes (vectorized)
// ===========================================================================
__global__ void convert_planes(const float* __restrict__ src, ushort* __restrict__ hi,
                               ushort* __restrict__ lo, int n4)
{
  int i = blockIdx.x * 256 + threadIdx.x;
  if (i >= n4) return;
  float4 v = ((const float4*)src)[i];
  ushort4 H, L;
  f2pair(v.x, H.x, L.x); f2pair(v.y, H.y, L.y);
  f2pair(v.z, H.z, L.z); f2pair(v.w, H.w, L.w);
  ((ushort4*)hi)[i] = H;
  ((ushort4*)lo)[i] = L;
}

// ===========================================================================
// 64x64 plane machinery (shared by small MFMA kernels)
// ===========================================================================
__device__ inline int swzb(int row, int kbyte) {
  return row * 128 + (kbyte ^ ((row & 7) << 4));
}

__device__ inline bf16x8 ldfrag(const ushort* plane, int row, int kbyte) {
  return *(const bf16x8*)((const char*)plane + swzb(row, kbyte));
}

__device__ inline void stage_nt(const float* __restrict__ src, int ld,
                                ushort* ph, ushort* pl, int t) {
#pragma unroll
  for (int rep = 0; rep < 4; ++rep) {
    int idx = t + rep * 256;
    int row = idx >> 4, f4 = idx & 15;
    float4 v = *(const float4*)(src + (size_t)row * ld + f4 * 4);
    ushort h0, h1, h2, h3, l0, l1, l2, l3;
    f2pair(v.x, h0, l0); f2pair(v.y, h1, l1);
    f2pair(v.z, h2, l2); f2pair(v.w, h3, l3);
    int byt = row * 128 + ((f4 * 8) ^ ((row & 7) << 4));
    *(ushort4*)((char*)ph + byt) = make_ushort4(h0, h1, h2, h3);
    *(ushort4*)((char*)pl + byt) = make_ushort4(l0, l1, l2, l3);
  }
}

__device__ inline void stage_nn(const float* __restrict__ src, int ld,
                                ushort* ph, ushort* pl, int t) {
#pragma unroll
  for (int rep = 0; rep < 4; ++rep) {
    int idx = t + rep * 256;
    int krow = idx >> 4, f4 = idx & 15;
    float4 v = *(const float4*)(src + (size_t)krow * ld + f4 * 4);
    float vv[4] = {v.x, v.y, v.z, v.w};
#pragma unroll
    for (int c = 0; c < 4; ++c) {
      int n = f4 * 4 + c;
      ushort hi, lo;
      f2pair(vv[c], hi, lo);
      int byt = n * 128 + ((krow * 2) ^ ((n & 7) << 4));
      *(ushort*)((char*)ph + byt) = hi;
      *(ushort*)((char*)pl + byt) = lo;
    }
  }
}

__device__ inline void tile_mma(const ushort* Ah, const ushort* Al,
                                const ushort* Bh, const ushort* Bl,
                                f32x4 acc[2][2], int lane, int wm, int wn) {
  bf16x8 aH[2][2], aL[2][2], bH[2][2], bL[2][2];
#pragma unroll
  for (int mi = 0; mi < 2; ++mi)
#pragma unroll
    for (int ki = 0; ki < 2; ++ki) {
      int kb = ki * 64 + ((lane >> 4) * 16);
      int ra = wm * 32 + mi * 16 + (lane & 15);
      int rb = wn * 32 + mi * 16 + (lane & 15);
      aH[mi][ki] = ldfrag(Ah, ra, kb);
      aL[mi][ki] = ldfrag(Al, ra, kb);
      bH[mi][ki] = ldfrag(Bh, rb, kb);
      bL[mi][ki] = ldfrag(Bl, rb, kb);
    }
#pragma unroll
  for (int mi = 0; mi < 2; ++mi)
#pragma unroll
    for (int ni = 0; ni < 2; ++ni)
#pragma unroll
      for (int ki = 0; ki < 2; ++ki) {
        acc[mi][ni] = __builtin_amdgcn_mfma_f32_16x16x32_bf16(
            aH[mi][ki], bH[ni][ki], acc[mi][ni], 0, 0, 0);
        acc[mi][ni] = __builtin_amdgcn_mfma_f32_16x16x32_bf16(
            aH[mi][ki], bL[ni][ki], acc[mi][ni], 0, 0, 0);
        acc[mi][ni] = __builtin_amdgcn_mfma_f32_16x16x32_bf16(
            aL[mi][ki], bH[ni][ki], acc[mi][ni], 0, 0, 0);
      }
}

// Batched per-(b,h) MFMA GEMM (64x64 tiles). Optional bf16-plane output.
__global__ __launch_bounds__(256) void gemm_heads_mfma(
    const float* __restrict__ A, const float* __restrict__ Bsrc,
    float* __restrict__ Cm,
    int kTilesPerSplit, int transB, int nBH,
    long long sAb, long long sAh, int lda,
    long long sBb, long long sBh, int ldb,
    long long sCb, long long sCh, int ldc, long long sCsplit,
    ushort* __restrict__ Hout, ushort* __restrict__ Lout)
{
  __shared__ __align__(16) ushort lds[16384];
  ushort* Ah = lds; ushort* Al = lds + 4096;
  ushort* Bh = lds + 8192; ushort* Bl = lds + 12288;
  const int t = threadIdx.x;
  const int z = blockIdx.z;
  const int split = z / nBH;
  const int bh = z % nBH;
  const int b = bh / HQ, h = bh % HQ;
  const float* Ap = A + (size_t)b * sAb + (size_t)h * sAh;
  const float* Bp = Bsrc + (size_t)b * sBb + (size_t)h * sBh;
  const int m0 = blockIdx.x * 64, n0 = blockIdx.y * 64;
  const int lane = t & 63, wv = t >> 6, wm = wv >> 1, wn = wv & 1;
  f32x4 zz = {0.f, 0.f, 0.f, 0.f};
  f32x4 acc[2][2] = {{zz, zz}, {zz, zz}};
  const int kbase = split * kTilesPerSplit * 64;
  for (int kt = 0; kt < kTilesPerSplit; ++kt) {
    int k0 = kbase + kt * 64;
    stage_nt(Ap + (size_t)m0 * lda + k0, lda, Ah, Al, t);
    if (transB)
      stage_nt(Bp + (size_t)n0 * ldb + k0, ldb, Bh, Bl, t);
    else
      stage_nn(Bp + (size_t)k0 * ldb + n0, ldb, Bh, Bl, t);
    __syncthreads();
    tile_mma(Ah, Al, Bh, Bl, acc, lane, wm, wn);
    __syncthreads();
  }
  if (Hout) {
    ushort* Hp = Hout + (size_t)b * sCb + (size_t)h * sCh + (size_t)split * sCsplit;
    ushort* Lp = Lout + (size_t)b * sCb + (size_t)h * sCh + (size_t)split * sCsplit;
#pragma unroll
    for (int mi = 0; mi < 2; ++mi)
#pragma unroll
      for (int ni = 0; ni < 2; ++ni) {
        int row = m0 + wm * 32 + mi * 16 + (lane >> 4) * 4;
        int col = n0 + wn * 32 + ni * 16 + (lane & 15);
#pragma unroll
        for (int r = 0; r < 4; ++r) {
          ushort hi, lo;
          f2pair(acc[mi][ni][r], hi, lo);
          Hp[(size_t)(row + r) * ldc + col] = hi;
          Lp[(size_t)(row + r) * ldc + col] = lo;
        }
      }
  } else {
    float* Cp = Cm + (size_t)b * sCb + (size_t)h * sCh + (size_t)split * sCsplit;
#pragma unroll
    for (int mi = 0; mi < 2; ++mi)
#pragma unroll
      for (int ni = 0; ni < 2; ++ni) {
        int row = m0 + wm * 32 + mi * 16 + (lane >> 4) * 4;
        int col = n0 + wn * 32 + ni * 16 + (lane & 15);
#pragma unroll
        for (int r = 0; r < 4; ++r)
          Cp[(size_t)(row + r) * ldc + col] = acc[mi][ni][r];
      }
  }
}

// ===========================================================================
// sim3_exp: E = exp(q_land @ k_chunk^T) (no-max exp; |sim3| small — validated)
// + per-chunk row-sum partials. Same staging/MFMA as gemm_heads (transB=1).
// grid (32 chunks, 24 bh), block 256
// ===========================================================================
__global__ __launch_bounds__(256) void sim3_exp(
    const float* __restrict__ ql, const float* __restrict__ qkv,
    float* __restrict__ E, float* __restrict__ rspart)
{
  __shared__ __align__(16) ushort lds[16384];
  __shared__ float rsq[2][64];
  ushort* Ah = lds; ushort* Al = lds + 4096;
  ushort* Bh = lds + 8192; ushort* Bl = lds + 12288;
  const int chunk = blockIdx.x, bh = blockIdx.y;
  const int b = bh / HQ, h = bh % HQ;
  const int t = threadIdx.x;
  const int lane = t & 63, wv = t >> 6, wm = wv >> 1, wn = wv & 1;
  stage_nt(ql + (size_t)bh * 4096, 64, Ah, Al, t);
  stage_nt(qkv + (size_t)(b * NQ + chunk * 64) * C3 + CQ + h * 64, C3, Bh, Bl, t);
  __syncthreads();
  f32x4 zz = {0.f, 0.f, 0.f, 0.f};
  f32x4 acc[2][2] = {{zz, zz}, {zz, zz}};
  tile_mma(Ah, Al, Bh, Bl, acc, lane, wm, wn);
  float* Cp = E + (size_t)bh * 131072 + chunk * 64;
  float e[2][2][4];
#pragma unroll
  for (int mi = 0; mi < 2; ++mi)
#pragma unroll
    for (int ni = 0; ni < 2; ++ni) {
      int row = wm * 32 + mi * 16 + (lane >> 4) * 4;
      int col = wn * 32 + ni * 16 + (lane & 15);
#pragma unroll
      for (int r = 0; r < 4; ++r) {
        float ev = __expf(acc[mi][ni][r]);
        e[mi][ni][r] = ev;
        Cp[(size_t)(row + r) * 2048 + col] = ev;
      }
    }
  // row-sum partials over this chunk's 64 columns (shuffle within 16-lane grp)
#pragma unroll
  for (int mi = 0; mi < 2; ++mi)
#pragma unroll
    for (int r = 0; r < 4; ++r) {
      float s = e[mi][0][r] + e[mi][1][r];
      s += __shfl_xor(s, 1); s += __shfl_xor(s, 2);
      s += __shfl_xor(s, 4); s += __shfl_xor(s, 8);
      if ((lane & 15) == 0)
        rsq[wn][wm * 32 + mi * 16 + ((lane >> 4) << 2) + r] = s;
    }
  __syncthreads();
  if (t < 64)
    rspart[(size_t)(bh * 32 + chunk) * 64 + t] = rsq[0][t] + rsq[1][t];
}

// rs (24x64) over 32 chunk-partials (wide, validated)
__global__ void rs_final(const float* __restrict__ rspart, float* __restrict__ rsf)
{
  int g = blockIdx.x * 256 + threadIdx.x;  // < 1536
  if (g >= 1536) return;
  int bh = g >> 6, j = g & 63;
  float s = 0.f;
#pragma unroll
  for (int c = 0; c < 32; ++c) s += rspart[(size_t)(bh * 32 + c) * 64 + j];
  rsf[g] = s;
}

// ===========================================================================
// Landmarks: mean over l=32 consecutive rows, q (already scaled) and k.
// ===========================================================================
__global__ void landmarks_kernel(const float* __restrict__ qkv,
                                 float* __restrict__ ql, float* __restrict__ kl)
{
  int idx = blockIdx.x * 256 + threadIdx.x;  // < 196608
  int sel = idx / 98304;
  int r = idx % 98304;
  int bh = r / 4096;
  int b = bh / HQ, h = bh % HQ;
  int i = (r % 4096) / 64;
  int dd = r & 63;
  const float* base = qkv + (size_t)(b * NQ + i * LQ) * C3 + sel * CQ + h * 64 + dd;
  float s = 0.f;
#pragma unroll
  for (int j = 0; j < LQ; ++j) s += base[(size_t)j * C3];
  float* outp = sel ? kl : ql;
  outp[bh * 4096 + i * 64 + dd] = s * (1.0f / 32.0f);
}

// ===========================================================================
// attn2 = softmax(q_land @ k_land^T) + global max row-sum / col-sum
// ===========================================================================
__global__ __launch_bounds__(256) void attn2_prep(
    const float* __restrict__ ql, const float* __restrict__ kl,
    float* __restrict__ attn2, float* __restrict__ scal)
{
  __shared__ float Q[64][68], Kl[64][68], S[64][68];
  __shared__ float red[128];
  const int bh = blockIdx.x;
  const int t = threadIdx.x;
#pragma unroll
  for (int rep = 0; rep < 4; ++rep) {
    int idx = t + rep * 256;
    int row = idx >> 4, f4 = idx & 15;
    *(float4*)&Q[row][f4 * 4] = *(const float4*)(ql + (size_t)bh * 4096 + row * 64 + f4 * 4);
    *(float4*)&Kl[row][f4 * 4] = *(const float4*)(kl + (size_t)bh * 4096 + row * 64 + f4 * 4);
  }
  __syncthreads();
  {
    int i = t >> 2;
    int jb = (t & 3) * 16;
    for (int jj = 0; jj < 16; ++jj) {
      int j = jb + jj;
      float s2 = 0.f;
#pragma unroll
      for (int kk = 0; kk < 64; ++kk) s2 = fmaf(Q[i][kk], Kl[j][kk], s2);
      S[i][j] = s2;
    }
  }
  __syncthreads();
  if (t < 64) {
    float mx = -INFINITY;
    for (int j = 0; j < 64; ++j) mx = fmaxf(mx, S[t][j]);
    float sum = 0.f;
    for (int j = 0; j < 64; ++j) { float e = expf(S[t][j] - mx); S[t][j] = e; sum += e; }
    float inv = 1.0f / sum;
    float rs = 0.f;
    for (int j = 0; j < 64; ++j) { float v = S[t][j] * inv; S[t][j] = v; rs += v; }
    red[t] = rs;
  }
  __syncthreads();
  if (t < 64) {
    float cs = 0.f;
    for (int i = 0; i < 64; ++i) cs += S[i][t];
    red[64 + t] = cs;
  }
  __syncthreads();
  if (t == 0) {
    float m1 = red[0], m2 = red[64];
    for (int j = 1; j < 64; ++j) { m1 = fmaxf(m1, red[j]); m2 = fmaxf(m2, red[64 + j]); }
    atomicMaxPosF(scal + 0, m1);
    atomicMaxPosF(scal + 1, m2);
  }
  for (int idx = t; idx < 4096; idx += 256)
    attn2[(size_t)bh * 4096 + idx] = S[idx >> 6][idx & 63];
}

// ===========================================================================
// Moore-Penrose pinv, 6 iterations, one block (1024 thr) per (b,h).
// Final write folds the attn3 row-normalizer into zinv columns:
//   zinv'[i][m] = Z[i][m] / rs[m]
// ===========================================================================
__device__ inline void mm64x(float (*D)[68], const float (*A)[68], const float (*B)[68],
                             int t, float scale)
{
  const int lane = t & 63, wv = t >> 6;
  float bcol[64];
#pragma unroll
  for (int kk = 0; kk < 64; ++kk) bcol[kk] = B[kk][lane];
#pragma unroll
  for (int rr = 0; rr < 4; ++rr) {
    int i = wv * 4 + rr;
    float acc2 = 0.f;
#pragma unroll
    for (int kk = 0; kk < 64; ++kk) acc2 = fmaf(A[i][kk], bcol[kk], acc2);
    D[i][lane] = acc2 * scale;
  }
}

__global__ __launch_bounds__(1024) void pinv_kernel(
    const float* __restrict__ attn2, const float* __restrict__ scal,
    const float* __restrict__ rsf, float* __restrict__ zinv)
{
  __shared__ float X[64][68], Z[64][68], P[64][68], Q[64][68], R[64][68];
  const int bh = blockIdx.x;
  const int t = threadIdx.x;
  const float denom = scal[0] * scal[1];
#pragma unroll
  for (int rep = 0; rep < 4; ++rep) {
    int idx = t + rep * 1024;
    X[idx >> 6][idx & 63] = attn2[(size_t)bh * 4096 + idx];
  }
  __syncthreads();
#pragma unroll
  for (int rep = 0; rep < 4; ++rep) {
    int idx = t + rep * 1024;
    int i = idx >> 6, j = idx & 63;
    Z[j][i] = X[i][j] / denom;
  }
  for (int it = 0; it < 6; ++it) {
    __syncthreads();
    mm64x(P, X, Z, t, 1.0f);
    __syncthreads();
    for (int idx = t; idx < 4096; idx += 1024) {
      int i = idx >> 6, j = idx & 63;
      Q[i][j] = (i == j ? 7.0f : 0.0f) - P[i][j];
    }
    __syncthreads();
    mm64x(R, P, Q, t, 1.0f);
    __syncthreads();
    for (int idx = t; idx < 4096; idx += 1024) {
      int i = idx >> 6, j = idx & 63;
      Q[i][j] = (i == j ? 15.0f : 0.0f) - R[i][j];
    }
    __syncthreads();
    mm64x(R, P, Q, t, 1.0f);
    __syncthreads();
    for (int idx = t; idx < 4096; idx += 1024) {
      int i = idx >> 6, j = idx & 63;
      Q[i][j] = (i == j ? 13.0f : 0.0f) - R[i][j];
    }
    __syncthreads();
    mm64x(P, Z, Q, t, 0.25f);
    __syncthreads();
    for (int idx = t; idx < 4096; idx += 1024) {
      int i = idx >> 6, j = idx & 63;
      Z[i][j] = P[i][j];
    }
  }
  __syncthreads();
  for (int idx = t; idx < 4096; idx += 1024)
    zinv[(size_t)bh * 4096 + idx] = Z[idx >> 6][idx & 63] / rsf[bh * 64 + (idx & 63)];
}

// ===========================================================================
// attn1 = softmax(q @ k_land^T) -> bf16 hi/lo planes, [b][n][h*64+m] layout
// ===========================================================================
__global__ __launch_bounds__(256) void attn1_kernel(
    const float* __restrict__ qkv, const float* __restrict__ kl,
    ushort* __restrict__ A1h, ushort* __restrict__ A1l)
{
  __shared__ float qs[64][68], klt[64][68];
  const int n0 = blockIdx.x * 64;
  const int bh = blockIdx.y;
  const int b = bh / HQ, h = bh % HQ;
  const int t = threadIdx.x;
#pragma unroll
  for (int rep = 0; rep < 4; ++rep) {
    int idx = t + rep * 256;
    int row = idx >> 4, f4 = idx & 15;
    *(float4*)&qs[row][f4 * 4] =
        *(const float4*)(qkv + (size_t)(b * NQ + n0 + row) * C3 + h * 64 + f4 * 4);
    float4 kv = *(const float4*)(kl + (size_t)bh * 4096 + row * 64 + f4 * 4);
    klt[f4 * 4 + 0][row] = kv.x; klt[f4 * 4 + 1][row] = kv.y;
    klt[f4 * 4 + 2][row] = kv.z; klt[f4 * 4 + 3][row] = kv.w;
  }
  __syncthreads();
  const int lane = t & 63, wv = t >> 6;
  float bcol[64];
#pragma unroll
  for (int kk = 0; kk < 64; ++kk) bcol[kk] = klt[kk][lane];
  for (int rr = 0; rr < 16; ++rr) {
    int i = wv * 16 + rr;
    float s = 0.f;
#pragma unroll
    for (int kk = 0; kk < 64; ++kk) s = fmaf(qs[i][kk], bcol[kk], s);
    float mx = s;
#pragma unroll
    for (int off = 32; off; off >>= 1) mx = fmaxf(mx, __shfl_xor(mx, off));
    float e = expf(s - mx);
    float sum = e;
#pragma unroll
    for (int off = 32; off; off >>= 1) sum += __shfl_xor(sum, off);
    float v = e / sum;
    ushort hi, lo;
    f2pair(v, hi, lo);
    size_t o = ((size_t)(b * NQ + n0 + i)) * CQ + h * 64 + lane;
    A1h[o] = hi;
    A1l[o] = lo;
  }
}

__global__ void reduce8_kernel(const float* __restrict__ part, float* __restrict__ outp)
{
  int idx = blockIdx.x * 256 + threadIdx.x;  // < 98304
  float s = 0.f;
#pragma unroll
  for (int r = 0; r < 8; ++r) s += part[(size_t)r * 98304 + idx];
  outp[idx] = s;
}

// ===========================================================================
// transpose T (24 x 64 x 2048 f32) -> TT planes (24 x 2048 x 64 bf16 hi/lo)
// ===========================================================================
__global__ __launch_bounds__(256) void transpose_T(
    const float* __restrict__ TBm, ushort* __restrict__ TTh, ushort* __restrict__ TTl)
{
  __shared__ float S[64][65];
  const int bh = blockIdx.y;
  const int n0 = blockIdx.x * 64;
  const int t = threadIdx.x;
  const float* src = TBm + (size_t)bh * 131072 + n0;
#pragma unroll
  for (int i = 0; i < 16; ++i) {
    int idx = t + i * 256;
    int m = idx >> 6, nn = idx & 63;
    S[m][nn] = src[(size_t)m * 2048 + nn];
  }
  __syncthreads();
  ushort* dh = TTh + (size_t)bh * 131072 + (size_t)n0 * 64;
  ushort* dl = TTl + (size_t)bh * 131072 + (size_t)n0 * 64;
#pragma unroll
  for (int i = 0; i < 16; ++i) {
    int idx = t + i * 256;
    int nn = idx >> 6, m = idx & 63;
    ushort hi, lo;
    f2pair(S[m][nn], hi, lo);
    dh[(size_t)nn * 64 + m] = hi;
    dl[(size_t)nn * 64 + m] = lo;
  }
}

__global__ void init_scal(float* s)
{
  if (threadIdx.x < 2) s[threadIdx.x] = 0.0f;
}

// ---------------------------------------------------------------------------
extern "C" void kernel_launch(void* const* d_in, const int* in_sizes, int n_in,
                              void* d_out, int out_size, void* d_ws, size_t ws_size,
                              hipStream_t stream)
{
  const float* x = (const float*)d_in[0];
  const float* w_qkv = (const float*)d_in[1];
  const float* w_proj = (const float*)d_in[2];
  const float* b_proj = (const float*)d_in[3];
  float* out = (float*)d_out;
  float* R = out + (size_t)BQ * NQ * CQ;  // attn output region (big scratch, dead before final write)

  // scratch inside attn region
  float* QKV = R;                       // 9437184
  float* AT3 = R + 9437184;             // 3145728 (E = exp(sim3), unnormalized)
  float* TBm = R + 12582912;            // 3145728
  float* W3P = R + 15728640;            // 786432
  float* W3V = R + 16515072;            // 98304
  float* UU  = R + 16613376;            // 98304
  float* RSP = R + 16711680;            // 49152
  float* RSF = R + 16760832;            // 1536
  ushort* xp_h = (ushort*)(R + 16762368);  // 3145728 us
  ushort* xp_l = xp_h + 3145728;
  ushort* wq_h = xp_l + 3145728;           // 1769472 us
  ushort* wq_l = wq_h + 1769472;
  ushort* gt_h = wq_l + 1769472;           // 1179648 us
  ushort* gt_l = gt_h + 1179648;

  // ws: survives into the final GEMMs
  float* ws = (float*)d_ws;
  float* QL = ws;                 // 98304
  float* KL = QL + 98304;         // 98304
  float* A2 = KL + 98304;         // 98304
  float* ZI = A2 + 98304;         // 98304
  float* SC = ZI + 98304;         // 32
  ushort* a1_h = (ushort*)(SC + 32);  // 3145728 us
  ushort* a1_l = a1_h + 3145728;
  ushort* tt_h = a1_l + 3145728;      // 3145728 us
  ushort* tt_l = tt_h + 3145728;

  init_scal<<<1, 64, 0, stream>>>(SC);

  convert_planes<<<3072, 256, 0, stream>>>(x, xp_h, xp_l, 786432);
  convert_planes<<<1728, 256, 0, stream>>>(w_qkv, wq_h, wq_l, 442368);

  // qkv = x @ w_qkv^T (q scaled by d^-0.5)
  gemm_bt3<<<dim3(32, 18, 1), 256, 0, stream>>>(
      xp_h, xp_l, wq_h, wq_l, nullptr, QKV,
      CQ, CQ, CQ, C3, 1, 1, 0, 0, 0, 0, 0, 0);

  landmarks_kernel<<<768, 256, 0, stream>>>(QKV, QL, KL);
  attn2_prep<<<24, 256, 0, stream>>>(QL, KL, A2, SC);

  // E = exp(sim3) + row-sum partials; rs = reduce
  sim3_exp<<<dim3(32, 24), 256, 0, stream>>>(QL, QKV, AT3, RSP);
  rs_final<<<6, 256, 0, stream>>>(RSP, RSF);

  // pinv, with zinv columns pre-divided by rs
  pinv_kernel<<<24, 1024, 0, stream>>>(A2, SC, RSF, ZI);

  attn1_kernel<<<dim3(32, 24), 256, 0, stream>>>(QKV, KL, a1_h, a1_l);

  // w3v = E @ v (8-way K split + reduce)   [normalizer folded into zinv]
  gemm_heads_mfma<<<dim3(1, 1, 192), 256, 0, stream>>>(
      AT3, QKV + 2 * CQ, W3P, 4, 0, 24,
      (long long)HQ * 131072, 131072, 2048,
      (long long)NQ * C3, 64, C3,
      (long long)HQ * 4096, 4096, 64, (long long)24 * 4096, nullptr, nullptr);
  reduce8_kernel<<<384, 256, 0, stream>>>(W3P, W3V);

  // u = zinv' @ w3v
  gemm_heads_mfma<<<dim3(1, 1, 24), 256, 0, stream>>>(
      ZI, W3V, UU, 1, 0, 24,
      (long long)HQ * 4096, 4096, 64,
      (long long)HQ * 4096, 4096, 64,
      (long long)HQ * 4096, 4096, 64, 0, nullptr, nullptr);

  // Gt[b][c][(h,m)] = sum_d w_proj[c][h*64+d] * u[b,h][m][d]  (planes out)
  gemm_heads_mfma<<<dim3(12, 1, 24), 256, 0, stream>>>(
      w_proj, UU, nullptr, 1, 1, 24,
      0, 64, CQ,
      (long long)HQ * 4096, 4096, 64,
      (long long)CQ * CQ, 64, CQ, 0, gt_h, gt_l);

  // T = zinv' @ E
  gemm_heads_mfma<<<dim3(1, 32, 24), 256, 0, stream>>>(
      ZI, AT3, TBm, 1, 0, 24,
      (long long)HQ * 4096, 4096, 64,
      (long long)HQ * 131072, 131072, 2048,
      (long long)HQ * 131072, 131072, 2048, 0, nullptr, nullptr);
  transpose_T<<<dim3(32, 24), 256, 0, stream>>>(TBm, tt_h, tt_l);

  // out = attn1cat @ Gt^T + bias (fuses outh-GEMM and proj)
  gemm_bt3<<<dim3(16, 6, 2), 256, 0, stream>>>(
      a1_h, a1_l, gt_h, gt_l, b_proj, out,
      CQ, CQ, CQ, CQ, 0, 1,
      (long long)NQ * CQ, 0, (long long)CQ * CQ, 0, (long long)NQ * CQ, 0);

  // attn = attn1 @ T (per-head, K=64)
  gemm_bt3<<<dim3(16, 16, 24), 256, 0, stream>>>(
      a1_h, a1_l, tt_h, tt_l, nullptr, R,
      64, CQ, 64, 2048, 0, HQ,
      (long long)NQ * CQ, 64,
      (long long)HQ * 131072, 131072,
      (long long)HQ * 4194304LL, 4194304);
}

// Round 15
// 377.963 us; speedup vs baseline: 1.0578x; 1.0578x over previous
//
#include <hip/hip_runtime.h>
#include <math.h>

// Problem constants
#define BQ 2
#define NQ 2048
#define CQ 768
#define HQ 12
#define DQ 64
#define MQ 64
#define LQ 32
#define C3 2304
#define BH 24
#define BN 4096

typedef short bf16x8 __attribute__((ext_vector_type(8)));
typedef float f32x4 __attribute__((ext_vector_type(4)));

__device__ inline void atomicMaxPosF(float* addr, float v) {
  atomicMax((int*)addr, __float_as_int(v));
}

// split f32 into bf16 hi + bf16 lo (truncation; combined rel err ~2^-17)
__device__ inline void f2pair(float f, ushort& hi, ushort& lo) {
  union { float f; unsigned u; } a; a.f = f;
  hi = (ushort)(a.u >> 16);
  union { unsigned u; float f; } h; h.u = ((unsigned)hi) << 16;
  union { float f; unsigned u; } b; b.f = f - h.f;
  lo = (ushort)(b.u >> 16);
}

// ===========================================================================
// 128x128 bf16x3 NT GEMM on pre-converted bf16 hi/lo planes.
// ===========================================================================
__device__ inline void stage_plane(const ushort* __restrict__ g, int ld,
                                   ushort* l, int t) {
#pragma unroll
  for (int i = 0; i < 4; ++i) {
    int flat = t + i * 256;
    int row = flat >> 3;
    int ch = (flat & 7) ^ (row & 7);
    __builtin_amdgcn_global_load_lds(
        (const __attribute__((address_space(1))) void*)(g + (size_t)row * ld + ch * 8),
        (__attribute__((address_space(3))) void*)(l + flat * 8), 16, 0, 0);
  }
}

__device__ inline bf16x8 rdfrag(const ushort* p, int row, int kb) {
  return *(const bf16x8*)((const char*)p + row * 128 + (kb ^ ((row & 7) << 4)));
}

__global__ __launch_bounds__(256) void gemm_bt3(
    const ushort* __restrict__ Ah, const ushort* __restrict__ Al,
    const ushort* __restrict__ Bh, const ushort* __restrict__ Bl,
    const float* __restrict__ bias, float* __restrict__ C,
    int Kdim, int lda, int ldb, int ldc, int qscale, int zH,
    long long sAb, long long sAh, long long sBb, long long sBh,
    long long sCb, long long sCh)
{
  __shared__ __align__(16) ushort lds[32768];
  ushort* LAh = lds;
  ushort* LAl = lds + 8192;
  ushort* LBh = lds + 16384;
  ushort* LBl = lds + 24576;
  const int t = threadIdx.x;
  const int z = blockIdx.z;
  const int b = z / zH, h = z % zH;
  const size_t aoff = (size_t)b * sAb + (size_t)h * sAh + (size_t)blockIdx.x * 128 * lda;
  const size_t boff = (size_t)b * sBb + (size_t)h * sBh + (size_t)blockIdx.y * 128 * ldb;
  const ushort* pAh = Ah + aoff;
  const ushort* pAl = Al + aoff;
  const ushort* pBh = Bh + boff;
  const ushort* pBl = Bl + boff;
  float* Cp = C + (size_t)b * sCb + (size_t)h * sCh;
  const int lane = t & 63, wv = t >> 6, wm = wv >> 1, wn = wv & 1;
  f32x4 zz = {0.f, 0.f, 0.f, 0.f};
  f32x4 acc[4][4] = {{zz, zz, zz, zz}, {zz, zz, zz, zz},
                     {zz, zz, zz, zz}, {zz, zz, zz, zz}};
  for (int k0 = 0; k0 < Kdim; k0 += 64) {
    stage_plane(pAh + k0, lda, LAh, t);
    stage_plane(pAl + k0, lda, LAl, t);
    stage_plane(pBh + k0, ldb, LBh, t);
    stage_plane(pBl + k0, ldb, LBl, t);
    __syncthreads();
#pragma unroll
    for (int kh = 0; kh < 2; ++kh) {
      const int kb = kh * 64 + ((lane >> 4) * 16);
      bf16x8 aH[4], aL[4], bHf[4], bLf[4];
#pragma unroll
      for (int i = 0; i < 4; ++i) {
        int ra = wm * 64 + i * 16 + (lane & 15);
        int rb = wn * 64 + i * 16 + (lane & 15);
        aH[i] = rdfrag(LAh, ra, kb);
        aL[i] = rdfrag(LAl, ra, kb);
        bHf[i] = rdfrag(LBh, rb, kb);
        bLf[i] = rdfrag(LBl, rb, kb);
      }
#pragma unroll
      for (int i = 0; i < 4; ++i)
#pragma unroll
        for (int j = 0; j < 4; ++j) {
          acc[i][j] = __builtin_amdgcn_mfma_f32_16x16x32_bf16(aH[i], bHf[j], acc[i][j], 0, 0, 0);
          acc[i][j] = __builtin_amdgcn_mfma_f32_16x16x32_bf16(aH[i], bLf[j], acc[i][j], 0, 0, 0);
          acc[i][j] = __builtin_amdgcn_mfma_f32_16x16x32_bf16(aL[i], bHf[j], acc[i][j], 0, 0, 0);
        }
    }
    __syncthreads();
  }
#pragma unroll
  for (int i = 0; i < 4; ++i)
#pragma unroll
    for (int j = 0; j < 4; ++j) {
      int row = blockIdx.x * 128 + wm * 64 + i * 16 + (lane >> 4) * 4;
      int col = blockIdx.y * 128 + wn * 64 + j * 16 + (lane & 15);
      float badd = bias ? bias[col] : 0.0f;
      float sc = (qscale && col < CQ) ? 0.125f : 1.0f;
#pragma unroll
      for (int r = 0; r < 4; ++r)
        Cp[(size_t)(row + r) * ldc + col] = acc[i][j][r] * sc + badd;
    }
}

// ===========================================================================
// f32 -> bf16 hi/lo planes (vectorized)
// ===========================================================================
__global__ void convert_planes(const float* __restrict__ src, ushort* __restrict__ hi,
                               ushort* __restrict__ lo, int n4)
{
  int i = blockIdx.x * 256 + threadIdx.x;
  if (i >= n4) return;
  float4 v = ((const float4*)src)[i];
  ushort4 H, L;
  f2pair(v.x, H.x, L.x); f2pair(v.y, H.y, L.y);
  f2pair(v.z, H.z, L.z); f2pair(v.w, H.w, L.w);
  ((ushort4*)hi)[i] = H;
  ((ushort4*)lo)[i] = L;
}

// ===========================================================================
// 64x64 plane machinery (shared by small MFMA kernels)
// ===========================================================================
__device__ inline int swzb(int row, int kbyte) {
  return row * 128 + (kbyte ^ ((row & 7) << 4));
}

__device__ inline bf16x8 ldfrag(const ushort* plane, int row, int kbyte) {
  return *(const bf16x8*)((const char*)plane + swzb(row, kbyte));
}

__device__ inline void stage_nt(const float* __restrict__ src, int ld,
                                ushort* ph, ushort* pl, int t) {
#pragma unroll
  for (int rep = 0; rep < 4; ++rep) {
    int idx = t + rep * 256;
    int row = idx >> 4, f4 = idx & 15;
    float4 v = *(const float4*)(src + (size_t)row * ld + f4 * 4);
    ushort h0, h1, h2, h3, l0, l1, l2, l3;
    f2pair(v.x, h0, l0); f2pair(v.y, h1, l1);
    f2pair(v.z, h2, l2); f2pair(v.w, h3, l3);
    int byt = row * 128 + ((f4 * 8) ^ ((row & 7) << 4));
    *(ushort4*)((char*)ph + byt) = make_ushort4(h0, h1, h2, h3);
    *(ushort4*)((char*)pl + byt) = make_ushort4(l0, l1, l2, l3);
  }
}

__device__ inline void stage_nn(const float* __restrict__ src, int ld,
                                ushort* ph, ushort* pl, int t) {
#pragma unroll
  for (int rep = 0; rep < 4; ++rep) {
    int idx = t + rep * 256;
    int krow = idx >> 4, f4 = idx & 15;
    float4 v = *(const float4*)(src + (size_t)krow * ld + f4 * 4);
    float vv[4] = {v.x, v.y, v.z, v.w};
#pragma unroll
    for (int c = 0; c < 4; ++c) {
      int n = f4 * 4 + c;
      ushort hi, lo;
      f2pair(vv[c], hi, lo);
      int byt = n * 128 + ((krow * 2) ^ ((n & 7) << 4));
      *(ushort*)((char*)ph + byt) = hi;
      *(ushort*)((char*)pl + byt) = lo;
    }
  }
}

__device__ inline void tile_mma(const ushort* Ah, const ushort* Al,
                                const ushort* Bh, const ushort* Bl,
                                f32x4 acc[2][2], int lane, int wm, int wn) {
  bf16x8 aH[2][2], aL[2][2], bH[2][2], bL[2][2];
#pragma unroll
  for (int mi = 0; mi < 2; ++mi)
#pragma unroll
    for (int ki = 0; ki < 2; ++ki) {
      int kb = ki * 64 + ((lane >> 4) * 16);
      int ra = wm * 32 + mi * 16 + (lane & 15);
      int rb = wn * 32 + mi * 16 + (lane & 15);
      aH[mi][ki] = ldfrag(Ah, ra, kb);
      aL[mi][ki] = ldfrag(Al, ra, kb);
      bH[mi][ki] = ldfrag(Bh, rb, kb);
      bL[mi][ki] = ldfrag(Bl, rb, kb);
    }
#pragma unroll
  for (int mi = 0; mi < 2; ++mi)
#pragma unroll
    for (int ni = 0; ni < 2; ++ni)
#pragma unroll
      for (int ki = 0; ki < 2; ++ki) {
        acc[mi][ni] = __builtin_amdgcn_mfma_f32_16x16x32_bf16(
            aH[mi][ki], bH[ni][ki], acc[mi][ni], 0, 0, 0);
        acc[mi][ni] = __builtin_amdgcn_mfma_f32_16x16x32_bf16(
            aH[mi][ki], bL[ni][ki], acc[mi][ni], 0, 0, 0);
        acc[mi][ni] = __builtin_amdgcn_mfma_f32_16x16x32_bf16(
            aL[mi][ki], bH[ni][ki], acc[mi][ni], 0, 0, 0);
      }
}

// Batched per-(b,h) MFMA GEMM (64x64 tiles). Optional bf16-plane output.
__global__ __launch_bounds__(256) void gemm_heads_mfma(
    const float* __restrict__ A, const float* __restrict__ Bsrc,
    float* __restrict__ Cm,
    int kTilesPerSplit, int transB, int nBH,
    long long sAb, long long sAh, int lda,
    long long sBb, long long sBh, int ldb,
    long long sCb, long long sCh, int ldc, long long sCsplit,
    ushort* __restrict__ Hout, ushort* __restrict__ Lout)
{
  __shared__ __align__(16) ushort lds[16384];
  ushort* Ah = lds; ushort* Al = lds + 4096;
  ushort* Bh = lds + 8192; ushort* Bl = lds + 12288;
  const int t = threadIdx.x;
  const int z = blockIdx.z;
  const int split = z / nBH;
  const int bh = z % nBH;
  const int b = bh / HQ, h = bh % HQ;
  const float* Ap = A + (size_t)b * sAb + (size_t)h * sAh;
  const float* Bp = Bsrc + (size_t)b * sBb + (size_t)h * sBh;
  const int m0 = blockIdx.x * 64, n0 = blockIdx.y * 64;
  const int lane = t & 63, wv = t >> 6, wm = wv >> 1, wn = wv & 1;
  f32x4 zz = {0.f, 0.f, 0.f, 0.f};
  f32x4 acc[2][2] = {{zz, zz}, {zz, zz}};
  const int kbase = split * kTilesPerSplit * 64;
  for (int kt = 0; kt < kTilesPerSplit; ++kt) {
    int k0 = kbase + kt * 64;
    stage_nt(Ap + (size_t)m0 * lda + k0, lda, Ah, Al, t);
    if (transB)
      stage_nt(Bp + (size_t)n0 * ldb + k0, ldb, Bh, Bl, t);
    else
      stage_nn(Bp + (size_t)k0 * ldb + n0, ldb, Bh, Bl, t);
    __syncthreads();
    tile_mma(Ah, Al, Bh, Bl, acc, lane, wm, wn);
    __syncthreads();
  }
  if (Hout) {
    ushort* Hp = Hout + (size_t)b * sCb + (size_t)h * sCh + (size_t)split * sCsplit;
    ushort* Lp = Lout + (size_t)b * sCb + (size_t)h * sCh + (size_t)split * sCsplit;
#pragma unroll
    for (int mi = 0; mi < 2; ++mi)
#pragma unroll
      for (int ni = 0; ni < 2; ++ni) {
        int row = m0 + wm * 32 + mi * 16 + (lane >> 4) * 4;
        int col = n0 + wn * 32 + ni * 16 + (lane & 15);
#pragma unroll
        for (int r = 0; r < 4; ++r) {
          ushort hi, lo;
          f2pair(acc[mi][ni][r], hi, lo);
          Hp[(size_t)(row + r) * ldc + col] = hi;
          Lp[(size_t)(row + r) * ldc + col] = lo;
        }
      }
  } else {
    float* Cp = Cm + (size_t)b * sCb + (size_t)h * sCh + (size_t)split * sCsplit;
#pragma unroll
    for (int mi = 0; mi < 2; ++mi)
#pragma unroll
      for (int ni = 0; ni < 2; ++ni) {
        int row = m0 + wm * 32 + mi * 16 + (lane >> 4) * 4;
        int col = n0 + wn * 32 + ni * 16 + (lane & 15);
#pragma unroll
        for (int r = 0; r < 4; ++r)
          Cp[(size_t)(row + r) * ldc + col] = acc[mi][ni][r];
      }
  }
}

// ===========================================================================
// sim3_exp: E = exp(q_land @ k_chunk^T) (no-max exp; |sim3| small — validated)
// + per-chunk row-sum partials. Same staging/MFMA as gemm_heads (transB=1).
// grid (32 chunks, 24 bh), block 256
// ===========================================================================
__global__ __launch_bounds__(256) void sim3_exp(
    const float* __restrict__ ql, const float* __restrict__ qkv,
    float* __restrict__ E, float* __restrict__ rspart)
{
  __shared__ __align__(16) ushort lds[16384];
  __shared__ float rsq[2][64];
  ushort* Ah = lds; ushort* Al = lds + 4096;
  ushort* Bh = lds + 8192; ushort* Bl = lds + 12288;
  const int chunk = blockIdx.x, bh = blockIdx.y;
  const int b = bh / HQ, h = bh % HQ;
  const int t = threadIdx.x;
  const int lane = t & 63, wv = t >> 6, wm = wv >> 1, wn = wv & 1;
  stage_nt(ql + (size_t)bh * 4096, 64, Ah, Al, t);
  stage_nt(qkv + (size_t)(b * NQ + chunk * 64) * C3 + CQ + h * 64, C3, Bh, Bl, t);
  __syncthreads();
  f32x4 zz = {0.f, 0.f, 0.f, 0.f};
  f32x4 acc[2][2] = {{zz, zz}, {zz, zz}};
  tile_mma(Ah, Al, Bh, Bl, acc, lane, wm, wn);
  float* Cp = E + (size_t)bh * 131072 + chunk * 64;
  float e[2][2][4];
#pragma unroll
  for (int mi = 0; mi < 2; ++mi)
#pragma unroll
    for (int ni = 0; ni < 2; ++ni) {
      int row = wm * 32 + mi * 16 + (lane >> 4) * 4;
      int col = wn * 32 + ni * 16 + (lane & 15);
#pragma unroll
      for (int r = 0; r < 4; ++r) {
        float ev = __expf(acc[mi][ni][r]);
        e[mi][ni][r] = ev;
        Cp[(size_t)(row + r) * 2048 + col] = ev;
      }
    }
  // row-sum partials over this chunk's 64 columns (shuffle within 16-lane grp)
#pragma unroll
  for (int mi = 0; mi < 2; ++mi)
#pragma unroll
    for (int r = 0; r < 4; ++r) {
      float s = e[mi][0][r] + e[mi][1][r];
      s += __shfl_xor(s, 1); s += __shfl_xor(s, 2);
      s += __shfl_xor(s, 4); s += __shfl_xor(s, 8);
      if ((lane & 15) == 0)
        rsq[wn][wm * 32 + mi * 16 + ((lane >> 4) << 2) + r] = s;
    }
  __syncthreads();
  if (t < 64)
    rspart[(size_t)(bh * 32 + chunk) * 64 + t] = rsq[0][t] + rsq[1][t];
}

// rs (24x64) over 32 chunk-partials (wide, validated)
__global__ void rs_final(const float* __restrict__ rspart, float* __restrict__ rsf)
{
  int g = blockIdx.x * 256 + threadIdx.x;  // < 1536
  if (g >= 1536) return;
  int bh = g >> 6, j = g & 63;
  float s = 0.f;
#pragma unroll
  for (int c = 0; c < 32; ++c) s += rspart[(size_t)(bh * 32 + c) * 64 + j];
  rsf[g] = s;
}

// ===========================================================================
// Landmarks: mean over l=32 consecutive rows, q (already scaled) and k.
// ===========================================================================
__global__ void landmarks_kernel(const float* __restrict__ qkv,
                                 float* __restrict__ ql, float* __restrict__ kl)
{
  int idx = blockIdx.x * 256 + threadIdx.x;  // < 196608
  int sel = idx / 98304;
  int r = idx % 98304;
  int bh = r / 4096;
  int b = bh / HQ, h = bh % HQ;
  int i = (r % 4096) / 64;
  int dd = r & 63;
  const float* base = qkv + (size_t)(b * NQ + i * LQ) * C3 + sel * CQ + h * 64 + dd;
  float s = 0.f;
#pragma unroll
  for (int j = 0; j < LQ; ++j) s += base[(size_t)j * C3];
  float* outp = sel ? kl : ql;
  outp[bh * 4096 + i * 64 + dd] = s * (1.0f / 32.0f);
}

// ===========================================================================
// attn2 = softmax(q_land @ k_land^T) + global max row-sum / col-sum
// ===========================================================================
__global__ __launch_bounds__(256) void attn2_prep(
    const float* __restrict__ ql, const float* __restrict__ kl,
    float* __restrict__ attn2, float* __restrict__ scal)
{
  __shared__ float Q[64][68], Kl[64][68], S[64][68];
  __shared__ float red[128];
  const int bh = blockIdx.x;
  const int t = threadIdx.x;
#pragma unroll
  for (int rep = 0; rep < 4; ++rep) {
    int idx = t + rep * 256;
    int row = idx >> 4, f4 = idx & 15;
    *(float4*)&Q[row][f4 * 4] = *(const float4*)(ql + (size_t)bh * 4096 + row * 64 + f4 * 4);
    *(float4*)&Kl[row][f4 * 4] = *(const float4*)(kl + (size_t)bh * 4096 + row * 64 + f4 * 4);
  }
  __syncthreads();
  {
    int i = t >> 2;
    int jb = (t & 3) * 16;
    for (int jj = 0; jj < 16; ++jj) {
      int j = jb + jj;
      float s2 = 0.f;
#pragma unroll
      for (int kk = 0; kk < 64; ++kk) s2 = fmaf(Q[i][kk], Kl[j][kk], s2);
      S[i][j] = s2;
    }
  }
  __syncthreads();
  if (t < 64) {
    float mx = -INFINITY;
    for (int j = 0; j < 64; ++j) mx = fmaxf(mx, S[t][j]);
    float sum = 0.f;
    for (int j = 0; j < 64; ++j) { float e = expf(S[t][j] - mx); S[t][j] = e; sum += e; }
    float inv = 1.0f / sum;
    float rs = 0.f;
    for (int j = 0; j < 64; ++j) { float v = S[t][j] * inv; S[t][j] = v; rs += v; }
    red[t] = rs;
  }
  __syncthreads();
  if (t < 64) {
    float cs = 0.f;
    for (int i = 0; i < 64; ++i) cs += S[i][t];
    red[64 + t] = cs;
  }
  __syncthreads();
  if (t == 0) {
    float m1 = red[0], m2 = red[64];
    for (int j = 1; j < 64; ++j) { m1 = fmaxf(m1, red[j]); m2 = fmaxf(m2, red[64 + j]); }
    atomicMaxPosF(scal + 0, m1);
    atomicMaxPosF(scal + 1, m2);
  }
  for (int idx = t; idx < 4096; idx += 256)
    attn2[(size_t)bh * 4096 + idx] = S[idx >> 6][idx & 63];
}

// ===========================================================================
// Moore-Penrose pinv, 6 iterations, one block (1024 thr) per (b,h).
// Final write folds the attn3 row-normalizer into zinv columns:
//   zinv'[i][m] = Z[i][m] / rs[m]
// ===========================================================================
__device__ inline void mm64x(float (*D)[68], const float (*A)[68], const float (*B)[68],
                             int t, float scale)
{
  const int lane = t & 63, wv = t >> 6;
  float bcol[64];
#pragma unroll
  for (int kk = 0; kk < 64; ++kk) bcol[kk] = B[kk][lane];
#pragma unroll
  for (int rr = 0; rr < 4; ++rr) {
    int i = wv * 4 + rr;
    float acc2 = 0.f;
#pragma unroll
    for (int kk = 0; kk < 64; ++kk) acc2 = fmaf(A[i][kk], bcol[kk], acc2);
    D[i][lane] = acc2 * scale;
  }
}

__global__ __launch_bounds__(1024) void pinv_kernel(
    const float* __restrict__ attn2, const float* __restrict__ scal,
    const float* __restrict__ rsf, float* __restrict__ zinv)
{
  __shared__ float X[64][68], Z[64][68], P[64][68], Q[64][68], R[64][68];
  const int bh = blockIdx.x;
  const int t = threadIdx.x;
  const float denom = scal[0] * scal[1];
#pragma unroll
  for (int rep = 0; rep < 4; ++rep) {
    int idx = t + rep * 1024;
    X[idx >> 6][idx & 63] = attn2[(size_t)bh * 4096 + idx];
  }
  __syncthreads();
#pragma unroll
  for (int rep = 0; rep < 4; ++rep) {
    int idx = t + rep * 1024;
    int i = idx >> 6, j = idx & 63;
    Z[j][i] = X[i][j] / denom;
  }
  for (int it = 0; it < 6; ++it) {
    __syncthreads();
    mm64x(P, X, Z, t, 1.0f);
    __syncthreads();
    for (int idx = t; idx < 4096; idx += 1024) {
      int i = idx >> 6, j = idx & 63;
      Q[i][j] = (i == j ? 7.0f : 0.0f) - P[i][j];
    }
    __syncthreads();
    mm64x(R, P, Q, t, 1.0f);
    __syncthreads();
    for (int idx = t; idx < 4096; idx += 1024) {
      int i = idx >> 6, j = idx & 63;
      Q[i][j] = (i == j ? 15.0f : 0.0f) - R[i][j];
    }
    __syncthreads();
    mm64x(R, P, Q, t, 1.0f);
    __syncthreads();
    for (int idx = t; idx < 4096; idx += 1024) {
      int i = idx >> 6, j = idx & 63;
      Q[i][j] = (i == j ? 13.0f : 0.0f) - R[i][j];
    }
    __syncthreads();
    mm64x(P, Z, Q, t, 0.25f);
    __syncthreads();
    for (int idx = t; idx < 4096; idx += 1024) {
      int i = idx >> 6, j = idx & 63;
      Z[i][j] = P[i][j];
    }
  }
  __syncthreads();
  for (int idx = t; idx < 4096; idx += 1024)
    zinv[(size_t)bh * 4096 + idx] = Z[idx >> 6][idx & 63] / rsf[bh * 64 + (idx & 63)];
}

// ===========================================================================
// attn1 = softmax(q @ k_land^T) -> bf16 hi/lo planes, [b][n][h*64+m] layout
// ===========================================================================
__global__ __launch_bounds__(256) void attn1_kernel(
    const float* __restrict__ qkv, const float* __restrict__ kl,
    ushort* __restrict__ A1h, ushort* __restrict__ A1l)
{
  __shared__ float qs[64][68], klt[64][68];
  const int n0 = blockIdx.x * 64;
  const int bh = blockIdx.y;
  const int b = bh / HQ, h = bh % HQ;
  const int t = threadIdx.x;
#pragma unroll
  for (int rep = 0; rep < 4; ++rep) {
    int idx = t + rep * 256;
    int row = idx >> 4, f4 = idx & 15;
    *(float4*)&qs[row][f4 * 4] =
        *(const float4*)(qkv + (size_t)(b * NQ + n0 + row) * C3 + h * 64 + f4 * 4);
    float4 kv = *(const float4*)(kl + (size_t)bh * 4096 + row * 64 + f4 * 4);
    klt[f4 * 4 + 0][row] = kv.x; klt[f4 * 4 + 1][row] = kv.y;
    klt[f4 * 4 + 2][row] = kv.z; klt[f4 * 4 + 3][row] = kv.w;
  }
  __syncthreads();
  const int lane = t & 63, wv = t >> 6;
  float bcol[64];
#pragma unroll
  for (int kk = 0; kk < 64; ++kk) bcol[kk] = klt[kk][lane];
  for (int rr = 0; rr < 16; ++rr) {
    int i = wv * 16 + rr;
    float s = 0.f;
#pragma unroll
    for (int kk = 0; kk < 64; ++kk) s = fmaf(qs[i][kk], bcol[kk], s);
    float mx = s;
#pragma unroll
    for (int off = 32; off; off >>= 1) mx = fmaxf(mx, __shfl_xor(mx, off));
    float e = expf(s - mx);
    float sum = e;
#pragma unroll
    for (int off = 32; off; off >>= 1) sum += __shfl_xor(sum, off);
    float v = e / sum;
    ushort hi, lo;
    f2pair(v, hi, lo);
    size_t o = ((size_t)(b * NQ + n0 + i)) * CQ + h * 64 + lane;
    A1h[o] = hi;
    A1l[o] = lo;
  }
}

__global__ void reduce8_kernel(const float* __restrict__ part, float* __restrict__ outp)
{
  int idx = blockIdx.x * 256 + threadIdx.x;  // < 98304
  float s = 0.f;
#pragma unroll
  for (int r = 0; r < 8; ++r) s += part[(size_t)r * 98304 + idx];
  outp[idx] = s;
}

// ===========================================================================
// transpose T (24 x 64 x 2048 f32) -> TT planes (24 x 2048 x 64 bf16 hi/lo)
// ===========================================================================
__global__ __launch_bounds__(256) void transpose_T(
    const float* __restrict__ TBm, ushort* __restrict__ TTh, ushort* __restrict__ TTl)
{
  __shared__ float S[64][65];
  const int bh = blockIdx.y;
  const int n0 = blockIdx.x * 64;
  const int t = threadIdx.x;
  const float* src = TBm + (size_t)bh * 131072 + n0;
#pragma unroll
  for (int i = 0; i < 16; ++i) {
    int idx = t + i * 256;
    int m = idx >> 6, nn = idx & 63;
    S[m][nn] = src[(size_t)m * 2048 + nn];
  }
  __syncthreads();
  ushort* dh = TTh + (size_t)bh * 131072 + (size_t)n0 * 64;
  ushort* dl = TTl + (size_t)bh * 131072 + (size_t)n0 * 64;
#pragma unroll
  for (int i = 0; i < 16; ++i) {
    int idx = t + i * 256;
    int nn = idx >> 6, m = idx & 63;
    ushort hi, lo;
    f2pair(S[m][nn], hi, lo);
    dh[(size_t)nn * 64 + m] = hi;
    dl[(size_t)nn * 64 + m] = lo;
  }
}

__global__ void init_scal(float* s)
{
  if (threadIdx.x < 2) s[threadIdx.x] = 0.0f;
}

// ---------------------------------------------------------------------------
extern "C" void kernel_launch(void* const* d_in, const int* in_sizes, int n_in,
                              void* d_out, int out_size, void* d_ws, size_t ws_size,
                              hipStream_t stream)
{
  const float* x = (const float*)d_in[0];
  const float* w_qkv = (const float*)d_in[1];
  const float* w_proj = (const float*)d_in[2];
  const float* b_proj = (const float*)d_in[3];
  float* out = (float*)d_out;
  float* R = out + (size_t)BQ * NQ * CQ;  // attn output region (big scratch, dead before final write)

  // scratch inside attn region
  float* QKV = R;                       // 9437184
  float* AT3 = R + 9437184;             // 3145728 (E = exp(sim3), unnormalized)
  float* TBm = R + 12582912;            // 3145728
  float* W3P = R + 15728640;            // 786432
  float* W3V = R + 16515072;            // 98304
  float* UU  = R + 16613376;            // 98304
  float* RSP = R + 16711680;            // 49152
  float* RSF = R + 16760832;            // 1536
  ushort* xp_h = (ushort*)(R + 16762368);  // 3145728 us
  ushort* xp_l = xp_h + 3145728;
  ushort* wq_h = xp_l + 3145728;           // 1769472 us
  ushort* wq_l = wq_h + 1769472;
  ushort* gt_h = wq_l + 1769472;           // 1179648 us
  ushort* gt_l = gt_h + 1179648;

  // ws: survives into the final GEMMs
  float* ws = (float*)d_ws;
  float* QL = ws;                 // 98304
  float* KL = QL + 98304;         // 98304
  float* A2 = KL + 98304;         // 98304
  float* ZI = A2 + 98304;         // 98304
  float* SC = ZI + 98304;         // 32
  ushort* a1_h = (ushort*)(SC + 32);  // 3145728 us
  ushort* a1_l = a1_h + 3145728;
  ushort* tt_h = a1_l + 3145728;      // 3145728 us
  ushort* tt_l = tt_h + 3145728;

  init_scal<<<1, 64, 0, stream>>>(SC);

  convert_planes<<<3072, 256, 0, stream>>>(x, xp_h, xp_l, 786432);
  convert_planes<<<1728, 256, 0, stream>>>(w_qkv, wq_h, wq_l, 442368);

  // qkv = x @ w_qkv^T (q scaled by d^-0.5)
  gemm_bt3<<<dim3(32, 18, 1), 256, 0, stream>>>(
      xp_h, xp_l, wq_h, wq_l, nullptr, QKV,
      CQ, CQ, CQ, C3, 1, 1, 0, 0, 0, 0, 0, 0);

  landmarks_kernel<<<768, 256, 0, stream>>>(QKV, QL, KL);
  attn2_prep<<<24, 256, 0, stream>>>(QL, KL, A2, SC);

  // E = exp(sim3) + row-sum partials; rs = reduce
  sim3_exp<<<dim3(32, 24), 256, 0, stream>>>(QL, QKV, AT3, RSP);
  rs_final<<<6, 256, 0, stream>>>(RSP, RSF);

  // pinv, with zinv columns pre-divided by rs
  pinv_kernel<<<24, 1024, 0, stream>>>(A2, SC, RSF, ZI);

  attn1_kernel<<<dim3(32, 24), 256, 0, stream>>>(QKV, KL, a1_h, a1_l);

  // w3v = E @ v (8-way K split + reduce)   [normalizer folded into zinv]
  gemm_heads_mfma<<<dim3(1, 1, 192), 256, 0, stream>>>(
      AT3, QKV + 2 * CQ, W3P, 4, 0, 24,
      (long long)HQ * 131072, 131072, 2048,
      (long long)NQ * C3, 64, C3,
      (long long)HQ * 4096, 4096, 64, (long long)24 * 4096, nullptr, nullptr);
  reduce8_kernel<<<384, 256, 0, stream>>>(W3P, W3V);

  // u = zinv' @ w3v
  gemm_heads_mfma<<<dim3(1, 1, 24), 256, 0, stream>>>(
      ZI, W3V, UU, 1, 0, 24,
      (long long)HQ * 4096, 4096, 64,
      (long long)HQ * 4096, 4096, 64,
      (long long)HQ * 4096, 4096, 64, 0, nullptr, nullptr);

  // Gt[b][c][(h,m)] = sum_d w_proj[c][h*64+d] * u[b,h][m][d]  (planes out)
  gemm_heads_mfma<<<dim3(12, 1, 24), 256, 0, stream>>>(
      w_proj, UU, nullptr, 1, 1, 24,
      0, 64, CQ,
      (long long)HQ * 4096, 4096, 64,
      (long long)CQ * CQ, 64, CQ, 0, gt_h, gt_l);

  // T = zinv' @ E
  gemm_heads_mfma<<<dim3(1, 32, 24), 256, 0, stream>>>(
      ZI, AT3, TBm, 1, 0, 24,
      (long long)HQ * 4096, 4096, 64,
      (long long)HQ * 131072, 131072, 2048,
      (long long)HQ * 131072, 131072, 2048, 0, nullptr, nullptr);
  transpose_T<<<dim3(32, 24), 256, 0, stream>>>(TBm, tt_h, tt_l);

  // out = attn1cat @ Gt^T + bias (fuses outh-GEMM and proj)
  gemm_bt3<<<dim3(16, 6, 2), 256, 0, stream>>>(
      a1_h, a1_l, gt_h, gt_l, b_proj, out,
      CQ, CQ, CQ, CQ, 0, 1,
      (long long)NQ * CQ, 0, (long long)CQ * CQ, 0, (long long)NQ * CQ, 0);

  // attn = attn1 @ T (per-head, K=64)
  gemm_bt3<<<dim3(16, 16, 24), 256, 0, stream>>>(
      a1_h, a1_l, tt_h, tt_l, nullptr, R,
      64, CQ, 64, 2048, 0, HQ,
      (long long)NQ * CQ, 64,
      (long long)HQ * 131072, 131072,
      (long long)HQ * 4194304LL, 4194304);
}